// Round 20
// baseline (96.773 us; speedup 1.0000x reference)
//
#include <hip/hip_runtime.h>
#include <hip/hip_bf16.h>
#include <math.h>

#define S_LEN 2048
#define DMODEL 1024
#define NHEADS 16
#define DHEAD 64
#define NBATCH 2
#define MROWS (NBATCH * S_LEN)   // 4096

typedef float f32x4 __attribute__((ext_vector_type(4)));
typedef unsigned short u16x8 __attribute__((ext_vector_type(8)));
typedef __bf16 bf16x8 __attribute__((ext_vector_type(8)));

__device__ __forceinline__ f32x4 mfma16(u16x8 a, u16x8 b, f32x4 c) {
    return __builtin_amdgcn_mfma_f32_16x16x32_bf16(
        __builtin_bit_cast(bf16x8, a), __builtin_bit_cast(bf16x8, b), c, 0, 0, 0);
}

// f32 -> bf16 round-to-nearest-even
__device__ __forceinline__ unsigned short f2bf(float f) {
    unsigned int u = __builtin_bit_cast(unsigned int, f);
    u += 0x7FFFu + ((u >> 16) & 1u);
    return (unsigned short)(u >> 16);
}

// packed f32x2 -> bf16x2 (RTNE), single HW instruction; low16 = lo
__device__ __forceinline__ unsigned int cvtpk(float lo, float hi) {
    unsigned int r;
    asm("v_cvt_pk_bf16_f32 %0, %1, %2" : "=v"(r) : "v"(lo), "v"(hi));
    return r;
}

// async global->LDS, 16B per lane; lds dest = wave-uniform base + lane*16
__device__ __forceinline__ void gl16(const void* g, void* l) {
    __builtin_amdgcn_global_load_lds(
        (const __attribute__((address_space(1))) unsigned int*)g,
        (__attribute__((address_space(3))) unsigned int*)l, 16, 0, 0);
}

// counted-vmcnt publishing barrier (sched_barrier fences both sides)
#define VMB(N) do { \
    asm volatile("s_waitcnt vmcnt(" #N ")" ::: "memory"); \
    __builtin_amdgcn_sched_barrier(0); \
    __builtin_amdgcn_s_barrier(); \
    __builtin_amdgcn_sched_barrier(0); } while (0)

// ---------------------------------------------------------------- cvt + pos
// blocks 0..2047: X. 2048..4095: Wq,Wk,Wv,Wo. 4096..4607: pos table.
__global__ __launch_bounds__(256) void cvt5(
    const float* __restrict__ X, const float* __restrict__ Wq,
    const float* __restrict__ Wk, const float* __restrict__ Wv,
    const float* __restrict__ Wo,
    unsigned short* __restrict__ Xbf, unsigned short* __restrict__ Wbf,
    float* __restrict__ pos)
{
    int b = blockIdx.x;
    if (b >= 4096) {
        int i = (b - 4096) * 256 + threadIdx.x;
        int s = i >> 6, d = i & 63;
        float theta = powf(10000.0f, (2.0f * (float)d) / 64.0f);
        float x = (float)s / theta;
        float v = (d & 1) ? cosf(x) : sinf(x);
        pos[i] = (s == 0) ? 0.0f : v;
        return;
    }
    const float* s; unsigned short* d; int t;
    if (b < 2048) { s = X; d = Xbf; t = b * 256 + threadIdx.x; }
    else {
        int z = (b - 2048) >> 9, bb = (b - 2048) & 511;
        s = (z == 0) ? Wq : (z == 1) ? Wk : (z == 2) ? Wv : Wo;
        d = Wbf + (z << 20);
        t = bb * 256 + threadIdx.x;
    }
    float4 a = *((const float4*)s + t * 2);
    float4 c = *((const float4*)s + t * 2 + 1);
    u16x8 o;
    o[0] = f2bf(a.x); o[1] = f2bf(a.y); o[2] = f2bf(a.z); o[3] = f2bf(a.w);
    o[4] = f2bf(c.x); o[5] = f2bf(c.y); o[6] = f2bf(c.z); o[7] = f2bf(c.w);
    *((u16x8*)d + t) = o;
}

// ---------------------------------------------------------------- QKV GEMM (bf16 in)
// gemm_out template x3: 128x128 tile, BK=64, 512 thr (8 waves 2Mx4N; wave
// 64x32, acc 4x2), grid (32, 24): z = y>>3 (block-uniform), n0 = (y&7)*128.
// 3-buffer 4-phase counted-vmcnt: stage one group {A0|A1|B0|B1} per phase
// into buffer p+2; boundary VMB(4) publishes p+1's 4 loads. LDS 3 x 32KB.
__global__ __launch_bounds__(512) void gemm_qkv(
    const unsigned short* __restrict__ Xbf, const unsigned short* __restrict__ Wbf,
    const float* __restrict__ pos,
    unsigned short* __restrict__ qb, unsigned short* __restrict__ kb,
    unsigned short* __restrict__ vt)
{
    const int z = blockIdx.y >> 3;
    const unsigned short* __restrict__ W = Wbf + (z << 20);
    __shared__ unsigned short L[3][16384];   // 32KB each: A @0, B @elem 8192
    const int t = threadIdx.x;               // 0..511
    const int lane = t & 63;
    const int w = t >> 6;
    const int wm = w >> 2, wn = w & 3;
    const int m0 = blockIdx.x * 128;
    const int n0 = (blockIdx.y & 7) * 128;
    const int ll = lane & 15, lg = lane >> 4;
    const int tr = t >> 3;
    const int ch = (t & 7) ^ (tr & 7);

    f32x4 acc[4][2] = {};

    const unsigned short* gA[2];
    const unsigned short* gB[2];
    #pragma unroll
    for (int i = 0; i < 2; i++) {
        gA[i] = Xbf + (m0 + i * 64 + tr) * 1024 + ch * 8;
        gB[i] = W + (n0 + i * 64 + tr) * 1024 + ch * 8;
    }

    const int sw0 = ((0 * 4 + lg) ^ (ll & 7)) * 16;
    const int sw1 = ((1 * 4 + lg) ^ (ll & 7)) * 16;
    const int aBase = (wm * 64 + ll) * 128;             // byte; + mf*2048 + sw
    const int bBase = 16384 + (wn * 32 + ll) * 128;     // byte; + nf*2048 + sw
    const int wdst = w * 8 * 64;                        // elem

    auto stA0 = [&](unsigned short* Ln) { gl16(gA[0], Ln + wdst);        gA[0] += 64; };
    auto stA1 = [&](unsigned short* Ln) { gl16(gA[1], Ln + 4096 + wdst); gA[1] += 64; };
    auto stB0 = [&](unsigned short* Ln) { gl16(gB[0], Ln + 8192 + wdst); gB[0] += 64; };
    auto stB1 = [&](unsigned short* Ln) { gl16(gB[1], Ln + 12288 + wdst); gB[1] += 64; };

    u16x8 bfv[2][2];
    auto loadB = [&](const char* bb) {
        #pragma unroll
        for (int nf = 0; nf < 2; nf++) {
            const char* p = bb + bBase + nf * 2048;
            bfv[nf][0] = *(const u16x8*)(p + sw0);
            bfv[nf][1] = *(const u16x8*)(p + sw1);
        }
    };
    auto quad = [&](int mf, const char* bb) {
        const char* pa = bb + aBase + mf * 2048;
        u16x8 a0 = *(const u16x8*)(pa + sw0);
        u16x8 a1 = *(const u16x8*)(pa + sw1);
        __builtin_amdgcn_s_setprio(1);
        #pragma unroll
        for (int nf = 0; nf < 2; nf++)
            acc[mf][nf] = mfma16(a0, bfv[nf][0], acc[mf][nf]);
        #pragma unroll
        for (int nf = 0; nf < 2; nf++)
            acc[mf][nf] = mfma16(a1, bfv[nf][1], acc[mf][nf]);
        __builtin_amdgcn_s_setprio(0);
    };

    auto ktile = [&](const char* bb, unsigned short* Ln, bool stg) {
        if (stg) stA0(Ln);
        loadB(bb);
        quad(0, bb);
        __builtin_amdgcn_s_barrier();
        if (stg) stA1(Ln);
        quad(1, bb);
        __builtin_amdgcn_s_barrier();
        if (stg) stB0(Ln);
        quad(2, bb);
        __builtin_amdgcn_s_barrier();
        if (stg) stB1(Ln);
        quad(3, bb);
    };

    stA0(L[0]); stA1(L[0]); stB0(L[0]); stB1(L[0]);
    stA0(L[1]); stA1(L[1]); stB0(L[1]); stB1(L[1]);
    VMB(4);                                   // tile 0 published; tile 1 in flight
    #pragma unroll 1
    for (int tt = 0; tt < 4; tt++) {
        ktile((const char*)L[0], L[2], true); VMB(4);
        ktile((const char*)L[1], L[0], true); VMB(4);
        ktile((const char*)L[2], L[1], true); VMB(4);
    }
    ktile((const char*)L[0], L[2], true); VMB(4);
    ktile((const char*)L[1], L[0], true); VMB(4);
    ktile((const char*)L[2], nullptr, false); VMB(0);
    ktile((const char*)L[0], nullptr, false);

    // epilogue: z is block-uniform
    if (z == 2) {
        // V^T: r=0..3 s-consecutive -> packed u64 store per (mf,nf)
        #pragma unroll
        for (int mf = 0; mf < 4; mf++) {
            const int row0 = m0 + wm * 64 + mf * 16 + lg * 4;
            const int b = row0 >> 11, s0 = row0 & 2047;
            #pragma unroll
            for (int nf = 0; nf < 2; nf++) {
                const int c = n0 + wn * 32 + nf * 16 + ll;   // h*64 + d
                const int h = c >> 6, d = c & 63;
                unsigned long long pk =
                    (unsigned long long)cvtpk(acc[mf][nf][0], acc[mf][nf][1]) |
                    ((unsigned long long)cvtpk(acc[mf][nf][2], acc[mf][nf][3]) << 32);
                *(unsigned long long*)&vt[(((b * NHEADS + h) * 64) + d) * S_LEN + s0] = pk;
            }
        }
    } else {
        unsigned short* const dst = (z == 0) ? qb : kb;
        const float pscale = (z == 0) ? 0.1803368801111244f : 1.0f;
        #pragma unroll
        for (int mf = 0; mf < 4; mf++) {
            #pragma unroll
            for (int nf = 0; nf < 2; nf++) {
                const int c = n0 + wn * 32 + nf * 16 + ll;
                const int h = c >> 6, d = c & 63;
                #pragma unroll
                for (int r = 0; r < 4; r++) {
                    const int row = m0 + wm * 64 + mf * 16 + lg * 4 + r;
                    const int b = row >> 11, s = row & 2047;
                    float v = acc[mf][nf][r] + pos[s * 64 + d];
                    v *= pscale;   // z==0: fold 1/sqrt(d_k)*log2(e); z==1: *1
                    dst[(((b * NHEADS + h) * S_LEN) + s) * 64 + d] = f2bf(v);
                }
            }
        }
    }
}

// ---------------------------------------------------------------- attention
// grid (32 bh, 16 x): bh in blockIdx.x keeps same-head blocks at id-stride 32
// (one XCD L2). Balance: qt = (x<8) ? 15-x : x-8, so the co-resident pair
// (x, x+8) computes (16-x)+(x+1) = 17 tiles on every CU (bijective over qt).
// 8 waves x 512 thr, QBLK=128, KVBLK=128. l = P x ones on the matrix pipe.
__global__ __launch_bounds__(512, 4) void attn_kernel(
    const unsigned short* __restrict__ qb,
    const unsigned short* __restrict__ kb,
    const unsigned short* __restrict__ vt,
    unsigned short* __restrict__ attnb)
{
    __shared__ unsigned short Klds[2][128 * 64];   // 16KB each
    __shared__ unsigned short Vlds[2][64 * 128];   // 16KB each
    __shared__ unsigned short Plds[8][16 * 64];    // per-wave 2KB; total 80KB

    const int bh = blockIdx.x;
    const int x = blockIdx.y;
    const int qt = (x < 8) ? (15 - x) : (x - 8);  // balanced + XCD-local

    const int lane = threadIdx.x & 63;
    const int w = threadIdx.x >> 6;               // 0..7
    const int lg = lane >> 4, ll = lane & 15;
    const int r8 = lane >> 3, ch = (lane & 7) ^ r8;
    const int r4 = lane >> 4, c16 = lane & 15;    // V-stage decomposition

    const unsigned short* Q = qb + bh * (S_LEN * 64);
    const unsigned short* K = kb + bh * (S_LEN * 64);
    const unsigned short* V = vt + bh * (64 * S_LEN);
    const int q0 = qt * 128 + w * 16;             // wave q-base

    u16x8 qf0 = *(const u16x8*)(Q + (q0 + ll) * 64 + lg * 8);
    u16x8 qf1 = *(const u16x8*)(Q + (q0 + ll) * 64 + 32 + lg * 8);

    // all-ones bf16 fragment for the l-MFMA (1.0bf16 = 0x3F80)
    u16x8 ones;
    #pragma unroll
    for (int i = 0; i < 8; i++) ones[i] = 0x3F80;

    f32x4 o_acc[4] = {};
    f32x4 l_acc = {};

    const int sw0 = ((0 * 4 + lg) ^ (ll & 7)) * 16;
    const int sw1 = ((1 * 4 + lg) ^ (ll & 7)) * 16;
    const char* kb0p0 = (const char*)&Klds[0][0] + ll * 128 + sw0;
    const char* kb0p1 = (const char*)&Klds[0][0] + ll * 128 + sw1;
    const char* kb1p0 = (const char*)&Klds[1][0] + ll * 128 + sw0;
    const char* kb1p1 = (const char*)&Klds[1][0] + ll * 128 + sw1;
    const char* vb0p0 = (const char*)&Vlds[0][0] + ll * 256 + sw0;
    const char* vb0p1 = (const char*)&Vlds[0][0] + ll * 256 + sw1;
    const char* vb1p0 = (const char*)&Vlds[1][0] + ll * 256 + sw0;
    const char* vb1p1 = (const char*)&Vlds[1][0] + ll * 256 + sw1;
    const int E = (ll & 7) << 4;
    char* pwb = (char*)&Plds[w][0] + (((ll * 128) + lg * 8) ^ (E & 16));
    const int pw_o0 = 0 ^ (E & 96), pw_o1 = 32 ^ (E & 96);
    const int pw_o2 = 64 ^ (E & 96), pw_o3 = 96 ^ (E & 96);
    const char* pr0 = (const char*)&Plds[w][0] + ll * 128 + sw0;
    const char* pr1 = (const char*)&Plds[w][0] + ll * 128 + sw1;
    unsigned short* kd0 = &Klds[0][(w * 16) * 64];
    unsigned short* kd1 = &Klds[1][(w * 16) * 64];
    unsigned short* vd0 = &Vlds[0][(w * 8) * 128];
    unsigned short* vd1 = &Vlds[1][(w * 8) * 128];
    const unsigned short* gk  = K + (w * 16 + r8) * 64 + ch * 8;
    const unsigned short* gva = V + (w * 8 + r4) * S_LEN + ((c16 ^ r4) * 8);
    const unsigned short* gvb = V + (w * 8 + 4 + r4) * S_LEN + ((c16 ^ (4 + r4)) * 8);
    const int dthr = w * 16 + ll - lg * 4;

    auto stage2 = [&](unsigned short* kd, unsigned short* vd) {
        gl16(gk, kd);
        gl16(gk + 512, kd + 512);
        gl16(gva, vd);
        gl16(gvb, vd + 512);
        gk += 128 * 64;
        gva += 128;
        gvb += 128;
    };

    auto tile_body = [&](const char* kp0, const char* kp1,
                         const char* vp0, const char* vp1, bool masked, int thr) {
        f32x4 sc[4] = {};
        __builtin_amdgcn_s_setprio(1);
        #pragma unroll
        for (int f = 0; f < 4; f++) {
            const u16x8 kfa = *(const u16x8*)(kp0 + f * 2048);
            sc[f] = mfma16(kfa, qf0, sc[f]);
            const u16x8 kfb = *(const u16x8*)(kp1 + f * 2048);
            sc[f] = mfma16(kfb, qf1, sc[f]);
        }
        __builtin_amdgcn_s_setprio(0);
        if (masked) {
            #pragma unroll
            for (int f = 0; f < 4; f++)
                #pragma unroll
                for (int r = 0; r < 4; r++)
                    if (f * 16 + r > thr) sc[f][r] = -1.0e9f;
        }
        #pragma unroll
        for (int f = 0; f < 4; f++)
            #pragma unroll
            for (int r = 0; r < 4; r++)
                sc[f][r] = __builtin_amdgcn_exp2f(sc[f][r]);
        *(unsigned long long*)(pwb + pw_o0) =
            (unsigned long long)cvtpk(sc[0][0], sc[0][1]) | ((unsigned long long)cvtpk(sc[0][2], sc[0][3]) << 32);
        *(unsigned long long*)(pwb + pw_o1) =
            (unsigned long long)cvtpk(sc[1][0], sc[1][1]) | ((unsigned long long)cvtpk(sc[1][2], sc[1][3]) << 32);
        *(unsigned long long*)(pwb + pw_o2) =
            (unsigned long long)cvtpk(sc[2][0], sc[2][1]) | ((unsigned long long)cvtpk(sc[2][2], sc[2][3]) << 32);
        *(unsigned long long*)(pwb + pw_o3) =
            (unsigned long long)cvtpk(sc[3][0], sc[3][1]) | ((unsigned long long)cvtpk(sc[3][2], sc[3][3]) << 32);
        const u16x8 pf0 = *(const u16x8*)pr0;
        const u16x8 pf1 = *(const u16x8*)pr1;
        __builtin_amdgcn_s_setprio(1);
        #pragma unroll
        for (int f = 0; f < 4; f++) {
            o_acc[f] = mfma16(pf0, *(const u16x8*)(vp0 + f * 4096), o_acc[f]);
            o_acc[f] = mfma16(pf1, *(const u16x8*)(vp1 + f * 4096), o_acc[f]);
        }
        l_acc = mfma16(pf0, ones, l_acc);   // l += P x 1 (matrix pipe)
        l_acc = mfma16(pf1, ones, l_acc);
        __builtin_amdgcn_s_setprio(0);
    };

    auto body128_full = [&](const char* kp0, const char* kp1,
                            const char* vp0, const char* vp1) {
        tile_body(kp0, kp1, vp0, vp1, false, 0);
        tile_body(kp0 + 8192, kp1 + 8192, vp0 + 128, vp1 + 128, false, 0);
    };
    auto body128_diag = [&](const char* kp0, const char* kp1,
                            const char* vp0, const char* vp1) {
        tile_body(kp0, kp1, vp0, vp1, true, dthr);
        if (w >= 4)   // waves 0-3: second half fully masked
            tile_body(kp0 + 8192, kp1 + 8192, vp0 + 128, vp1 + 128, true, dthr - 64);
    };

    stage2(kd0, vd0);                      // tile 0 -> buf0
    __syncthreads();                       // buf0 ready

    int p = 0;
    while (p + 2 <= qt) {                  // two full 128-tiles
        stage2(kd1, vd1);
        body128_full(kb0p0, kb0p1, vb0p0, vb0p1);
        __syncthreads();
        stage2(kd0, vd0);
        body128_full(kb1p0, kb1p1, vb1p0, vb1p1);
        __syncthreads();
        p += 2;
    }
    if (p < qt) {
        stage2(kd1, vd1);
        body128_full(kb0p0, kb0p1, vb0p0, vb0p1);
        __syncthreads();
        body128_diag(kb1p0, kb1p1, vb1p0, vb1p1);
    } else {
        body128_diag(kb0p0, kb0p1, vb0p0, vb0p1);
    }

    const int bb = bh >> 4, h = bh & 15;
    const float lr0 = 1.0f / l_acc[0];
    const float lr1 = 1.0f / l_acc[1];
    const float lr2 = 1.0f / l_acc[2];
    const float lr3 = 1.0f / l_acc[3];
    #pragma unroll
    for (int f = 0; f < 4; f++) {
        const int colbase = h * 64 + f * 16 + ll;
        attnb[(bb * S_LEN + q0 + lg * 4 + 0) * DMODEL + colbase] = f2bf(o_acc[f][0] * lr0);
        attnb[(bb * S_LEN + q0 + lg * 4 + 1) * DMODEL + colbase] = f2bf(o_acc[f][1] * lr1);
        attnb[(bb * S_LEN + q0 + lg * 4 + 2) * DMODEL + colbase] = f2bf(o_acc[f][2] * lr2);
        attnb[(bb * S_LEN + q0 + lg * 4 + 3) * DMODEL + colbase] = f2bf(o_acc[f][3] * lr3);
    }
}

// ---------------------------------------------------------------- out GEMM
// out = attn @ Wo^T + X. 4-phase counted-vmcnt: 128x128 tile, BK=64, 512 thr
// (8 waves 2Mx4N; wave 64x32, acc 4x2), grid (32,8) = 256 blocks = one
// generation. LDS 3 x 32KB. Boundary VMB(4); tail VMB(0).
__global__ __launch_bounds__(512) void gemm_out(
    const unsigned short* __restrict__ Abf,
    const unsigned short* __restrict__ Wbf,
    const float* __restrict__ X,
    float* __restrict__ out)
{
    const unsigned short* __restrict__ W = Wbf + (3u << 20);
    __shared__ unsigned short L[3][16384];   // 32KB each: A @0, B @elem 8192
    const int t = threadIdx.x;               // 0..511
    const int lane = t & 63;
    const int w = t >> 6;
    const int wm = w >> 2, wn = w & 3;
    const int m0 = blockIdx.x * 128;
    const int n0 = blockIdx.y * 128;
    const int ll = lane & 15, lg = lane >> 4;
    const int tr = t >> 3;
    const int ch = (t & 7) ^ (tr & 7);

    f32x4 acc[4][2] = {};

    const unsigned short* gA[2];
    const unsigned short* gB[2];
    #pragma unroll
    for (int i = 0; i < 2; i++) {
        gA[i] = Abf + (m0 + i * 64 + tr) * 1024 + ch * 8;
        gB[i] = W + (n0 + i * 64 + tr) * 1024 + ch * 8;
    }

    const int sw0 = ((0 * 4 + lg) ^ (ll & 7)) * 16;
    const int sw1 = ((1 * 4 + lg) ^ (ll & 7)) * 16;
    const int aBase = (wm * 64 + ll) * 128;             // byte; + mf*2048 + sw
    const int bBase = 16384 + (wn * 32 + ll) * 128;     // byte; + nf*2048 + sw
    const int wdst = w * 8 * 64;                        // elem

    auto stA0 = [&](unsigned short* Ln) { gl16(gA[0], Ln + wdst);        gA[0] += 64; };
    auto stA1 = [&](unsigned short* Ln) { gl16(gA[1], Ln + 4096 + wdst); gA[1] += 64; };
    auto stB0 = [&](unsigned short* Ln) { gl16(gB[0], Ln + 8192 + wdst); gB[0] += 64; };
    auto stB1 = [&](unsigned short* Ln) { gl16(gB[1], Ln + 12288 + wdst); gB[1] += 64; };

    u16x8 bfv[2][2];
    auto loadB = [&](const char* bb) {
        #pragma unroll
        for (int nf = 0; nf < 2; nf++) {
            const char* p = bb + bBase + nf * 2048;
            bfv[nf][0] = *(const u16x8*)(p + sw0);
            bfv[nf][1] = *(const u16x8*)(p + sw1);
        }
    };
    auto quad = [&](int mf, const char* bb) {
        const char* pa = bb + aBase + mf * 2048;
        u16x8 a0 = *(const u16x8*)(pa + sw0);
        u16x8 a1 = *(const u16x8*)(pa + sw1);
        __builtin_amdgcn_s_setprio(1);
        #pragma unroll
        for (int nf = 0; nf < 2; nf++)
            acc[mf][nf] = mfma16(a0, bfv[nf][0], acc[mf][nf]);
        #pragma unroll
        for (int nf = 0; nf < 2; nf++)
            acc[mf][nf] = mfma16(a1, bfv[nf][1], acc[mf][nf]);
        __builtin_amdgcn_s_setprio(0);
    };

    auto ktile = [&](const char* bb, unsigned short* Ln, bool stg) {
        if (stg) stA0(Ln);
        loadB(bb);
        quad(0, bb);
        __builtin_amdgcn_s_barrier();
        if (stg) stA1(Ln);
        quad(1, bb);
        __builtin_amdgcn_s_barrier();
        if (stg) stB0(Ln);
        quad(2, bb);
        __builtin_amdgcn_s_barrier();
        if (stg) stB1(Ln);
        quad(3, bb);
    };

    stA0(L[0]); stA1(L[0]); stB0(L[0]); stB1(L[0]);
    stA0(L[1]); stA1(L[1]); stB0(L[1]); stB1(L[1]);
    VMB(4);                                   // tile 0 published; tile 1 in flight
    #pragma unroll 1
    for (int tt = 0; tt < 4; tt++) {
        ktile((const char*)L[0], L[2], true); VMB(4);
        ktile((const char*)L[1], L[0], true); VMB(4);
        ktile((const char*)L[2], L[1], true); VMB(4);
    }
    ktile((const char*)L[0], L[2], true); VMB(4);
    ktile((const char*)L[1], L[0], true); VMB(4);
    ktile((const char*)L[2], nullptr, false); VMB(0);
    ktile((const char*)L[0], nullptr, false);

    #pragma unroll
    for (int mf = 0; mf < 4; mf++)
        #pragma unroll
        for (int nf = 0; nf < 2; nf++)
            #pragma unroll
            for (int r = 0; r < 4; r++) {
                const int row = m0 + wm * 64 + mf * 16 + lg * 4 + r;
                const int col = n0 + wn * 32 + nf * 16 + ll;
                out[row * 1024 + col] = acc[mf][nf][r] + X[row * 1024 + col];
            }
}

// ---------------------------------------------------------------- launch
extern "C" void kernel_launch(void* const* d_in, const int* in_sizes, int n_in,
                              void* d_out, int out_size, void* d_ws, size_t ws_size,
                              hipStream_t stream) {
    const float* X  = (const float*)d_in[0];
    const float* Wq = (const float*)d_in[1];
    const float* Wk = (const float*)d_in[2];
    const float* Wv = (const float*)d_in[3];
    const float* Wo = (const float*)d_in[4];
    float* out = (float*)d_out;

    char* ws = (char*)d_ws;
    float*          pos  = (float*)(ws);                                   // 512 KB
    unsigned short* Xbf  = (unsigned short*)(ws + (512u << 10));           // 8 MB (reused as attb)
    unsigned short* Wbf  = (unsigned short*)(ws + (512u << 10) + (8u  << 20));  // 8 MB (4 stacked)
    unsigned short* qb   = (unsigned short*)(ws + (512u << 10) + (16u << 20));
    unsigned short* kb   = (unsigned short*)(ws + (512u << 10) + (24u << 20));
    unsigned short* vt   = (unsigned short*)(ws + (512u << 10) + (32u << 20));
    unsigned short* attb = Xbf;   // Xbf dead after gemm_qkv; reuse for attn output

    cvt5<<<dim3(4608), dim3(256), 0, stream>>>(X, Wq, Wk, Wv, Wo, Xbf, Wbf, pos);
    gemm_qkv<<<dim3(32, 24), dim3(512), 0, stream>>>(Xbf, Wbf, pos, qb, kb, vt);
    attn_kernel<<<dim3(32, 16), dim3(512), 0, stream>>>(qb, kb, vt, attb);
    gemm_out<<<dim3(32, 8), dim3(512), 0, stream>>>(attb, Wbf, X, out);
}

// Round 21
// 89.764 us; speedup vs baseline: 1.0781x; 1.0781x over previous
//
#include <hip/hip_runtime.h>
#include <hip/hip_bf16.h>
#include <math.h>

#define S_LEN 2048
#define DMODEL 1024
#define NHEADS 16
#define DHEAD 64
#define NBATCH 2
#define MROWS (NBATCH * S_LEN)   // 4096

typedef float f32x4 __attribute__((ext_vector_type(4)));
typedef unsigned short u16x8 __attribute__((ext_vector_type(8)));
typedef __bf16 bf16x8 __attribute__((ext_vector_type(8)));

__device__ __forceinline__ f32x4 mfma16(u16x8 a, u16x8 b, f32x4 c) {
    return __builtin_amdgcn_mfma_f32_16x16x32_bf16(
        __builtin_bit_cast(bf16x8, a), __builtin_bit_cast(bf16x8, b), c, 0, 0, 0);
}

// f32 -> bf16 round-to-nearest-even
__device__ __forceinline__ unsigned short f2bf(float f) {
    unsigned int u = __builtin_bit_cast(unsigned int, f);
    u += 0x7FFFu + ((u >> 16) & 1u);
    return (unsigned short)(u >> 16);
}

// packed f32x2 -> bf16x2 (RTNE), single HW instruction; low16 = lo
__device__ __forceinline__ unsigned int cvtpk(float lo, float hi) {
    unsigned int r;
    asm("v_cvt_pk_bf16_f32 %0, %1, %2" : "=v"(r) : "v"(lo), "v"(hi));
    return r;
}

// async global->LDS, 16B per lane; lds dest = wave-uniform base + lane*16
__device__ __forceinline__ void gl16(const void* g, void* l) {
    __builtin_amdgcn_global_load_lds(
        (const __attribute__((address_space(1))) unsigned int*)g,
        (__attribute__((address_space(3))) unsigned int*)l, 16, 0, 0);
}

// counted-vmcnt publishing barrier (sched_barrier fences both sides)
#define VMB(N) do { \
    asm volatile("s_waitcnt vmcnt(" #N ")" ::: "memory"); \
    __builtin_amdgcn_sched_barrier(0); \
    __builtin_amdgcn_s_barrier(); \
    __builtin_amdgcn_sched_barrier(0); } while (0)

// ---------------------------------------------------------------- cvt + pos
// blocks 0..2047: X. 2048..4095: Wq,Wk,Wv,Wo. 4096..4607: pos table.
__global__ __launch_bounds__(256) void cvt5(
    const float* __restrict__ X, const float* __restrict__ Wq,
    const float* __restrict__ Wk, const float* __restrict__ Wv,
    const float* __restrict__ Wo,
    unsigned short* __restrict__ Xbf, unsigned short* __restrict__ Wbf,
    float* __restrict__ pos)
{
    int b = blockIdx.x;
    if (b >= 4096) {
        int i = (b - 4096) * 256 + threadIdx.x;
        int s = i >> 6, d = i & 63;
        float theta = powf(10000.0f, (2.0f * (float)d) / 64.0f);
        float x = (float)s / theta;
        float v = (d & 1) ? cosf(x) : sinf(x);
        pos[i] = (s == 0) ? 0.0f : v;
        return;
    }
    const float* s; unsigned short* d; int t;
    if (b < 2048) { s = X; d = Xbf; t = b * 256 + threadIdx.x; }
    else {
        int z = (b - 2048) >> 9, bb = (b - 2048) & 511;
        s = (z == 0) ? Wq : (z == 1) ? Wk : (z == 2) ? Wv : Wo;
        d = Wbf + (z << 20);
        t = bb * 256 + threadIdx.x;
    }
    float4 a = *((const float4*)s + t * 2);
    float4 c = *((const float4*)s + t * 2 + 1);
    u16x8 o;
    o[0] = f2bf(a.x); o[1] = f2bf(a.y); o[2] = f2bf(a.z); o[3] = f2bf(a.w);
    o[4] = f2bf(c.x); o[5] = f2bf(c.y); o[6] = f2bf(c.z); o[7] = f2bf(c.w);
    *((u16x8*)d + t) = o;
}

// ---------------------------------------------------------------- QKV GEMM (bf16 in)
// 256x192 tile, BK=64, 512 thr (8 waves, 2Mx4N; wave = 128x48), grid (16,16)
// = 256 blocks = one full-machine generation. W treated as one [3072][1024]
// matrix; epilogue derives z = col>>10 per nf (wave-uniform). LDS 2 x 56KB.
// Stage order per tile (7 gl16/thread): B0B1 | B2 | A0A2 | A1A3.
// Counted waits: mid-tile vmcnt(5); boundary vmcnt(2). Never 0 until tail.
__global__ __launch_bounds__(512) void gemm_qkv(
    const unsigned short* __restrict__ Xbf, const unsigned short* __restrict__ Wbf,
    const float* __restrict__ pos,
    unsigned short* __restrict__ qb, unsigned short* __restrict__ kb,
    unsigned short* __restrict__ vt)
{
    __shared__ unsigned short L[2][28672];   // 56KB per buffer
    const int t = threadIdx.x;               // 0..511
    const int lane = t & 63;
    const int w = t >> 6;                    // 0..7
    const int wm = w >> 2, wn = w & 3;
    const int m0 = blockIdx.x * 256;
    const int nb = blockIdx.y * 192;         // global col in [0,3072)
    const int ll = lane & 15, lg = lane >> 4;
    const int tr = t >> 3;                   // 0..63
    const int ch = (t & 7) ^ (tr & 7);

    f32x4 acc[8][3] = {};

    const unsigned short* gA[4];
    const unsigned short* gB[3];
    #pragma unroll
    for (int i = 0; i < 4; i++)
        gA[i] = Xbf + (m0 + i * 64 + tr) * 1024 + ch * 8;
    #pragma unroll
    for (int i = 0; i < 3; i++)
        gB[i] = Wbf + (nb + i * 64 + tr) * 1024 + ch * 8;

    const int sw0 = ((0 * 4 + lg) ^ (ll & 7)) * 16;
    const int sw1 = ((1 * 4 + lg) ^ (ll & 7)) * 16;
    const int aBase = (wm * 128 + ll) * 128;
    const int bBase = 32768 + (wn * 48 + ll) * 128;
    const int wdst = w * 8 * 64;

    auto stB01 = [&](unsigned short* Ln) {
        gl16(gB[0], Ln + 16384 + wdst);          gB[0] += 64;
        gl16(gB[1], Ln + 16384 + 4096 + wdst);   gB[1] += 64;
    };
    auto stB2 = [&](unsigned short* Ln) {
        gl16(gB[2], Ln + 16384 + 8192 + wdst);   gB[2] += 64;
    };
    auto stA02 = [&](unsigned short* Ln) {
        gl16(gA[0], Ln + wdst);                  gA[0] += 64;
        gl16(gA[2], Ln + 8192 + wdst);           gA[2] += 64;
    };
    auto stA13 = [&](unsigned short* Ln) {
        gl16(gA[1], Ln + 4096 + wdst);           gA[1] += 64;
        gl16(gA[3], Ln + 12288 + wdst);          gA[3] += 64;
    };

    u16x8 bf[3][2];
    auto loadB = [&](const char* bB) {
        #pragma unroll
        for (int nf = 0; nf < 3; nf++) {
            const char* p = bB + bBase + nf * 2048;
            bf[nf][0] = *(const u16x8*)(p + sw0);
            bf[nf][1] = *(const u16x8*)(p + sw1);
        }
    };
    auto quad = [&](int q, const char* bA) {
        const char* pa = bA + aBase + q * 4096;
        u16x8 a00 = *(const u16x8*)(pa + sw0);
        u16x8 a01 = *(const u16x8*)(pa + sw1);
        u16x8 a10 = *(const u16x8*)(pa + 2048 + sw0);
        u16x8 a11 = *(const u16x8*)(pa + 2048 + sw1);
        __builtin_amdgcn_s_setprio(1);
        #pragma unroll
        for (int nf = 0; nf < 3; nf++) {
            acc[q * 2 + 0][nf] = mfma16(a00, bf[nf][0], acc[q * 2 + 0][nf]);
            acc[q * 2 + 1][nf] = mfma16(a10, bf[nf][0], acc[q * 2 + 1][nf]);
        }
        #pragma unroll
        for (int nf = 0; nf < 3; nf++) {
            acc[q * 2 + 0][nf] = mfma16(a01, bf[nf][1], acc[q * 2 + 0][nf]);
            acc[q * 2 + 1][nf] = mfma16(a11, bf[nf][1], acc[q * 2 + 1][nf]);
        }
        __builtin_amdgcn_s_setprio(0);
    };

    stB01(L[0]); stB2(L[0]); stA02(L[0]); stA13(L[0]);
    VMB(2);

    #pragma unroll 1
    for (int tt = 0; tt < 15; tt++) {
        const char* bA = (const char*)L[tt & 1];
        unsigned short* Ln = L[(tt + 1) & 1];
        stB01(Ln);
        loadB(bA);
        quad(0, bA);
        __builtin_amdgcn_s_barrier();
        stB2(Ln);
        quad(1, bA);
        __builtin_amdgcn_s_barrier();
        stA02(Ln);
        VMB(5);
        quad(2, bA);
        __builtin_amdgcn_s_barrier();
        stA13(Ln);
        quad(3, bA);
        VMB(2);
    }
    {
        const char* bA = (const char*)L[1];
        loadB(bA);
        quad(0, bA);
        __builtin_amdgcn_s_barrier();
        quad(1, bA);
        VMB(0);
        quad(2, bA);
        quad(3, bA);
    }

    #pragma unroll
    for (int nf = 0; nf < 3; nf++) {
        const int c = nb + wn * 48 + nf * 16 + ll;   // global col 0..3071
        const int zz = c >> 10;                      // wave-uniform
        const int lc = c & 1023;
        const int h = lc >> 6, d = lc & 63;
        if (zz == 2) {
            #pragma unroll
            for (int mf = 0; mf < 8; mf++) {
                const int row0 = m0 + wm * 128 + mf * 16 + lg * 4;
                const int b = row0 >> 11, s0 = row0 & 2047;
                unsigned long long pk =
                    (unsigned long long)cvtpk(acc[mf][nf][0], acc[mf][nf][1]) |
                    ((unsigned long long)cvtpk(acc[mf][nf][2], acc[mf][nf][3]) << 32);
                *(unsigned long long*)&vt[(((b * NHEADS + h) * 64) + d) * S_LEN + s0] = pk;
            }
        } else {
            unsigned short* const dst = (zz == 0) ? qb : kb;
            const float pscale = (zz == 0) ? 0.1803368801111244f : 1.0f;
            #pragma unroll
            for (int mf = 0; mf < 8; mf++) {
                #pragma unroll
                for (int r = 0; r < 4; r++) {
                    const int row = m0 + wm * 128 + mf * 16 + lg * 4 + r;
                    const int b = row >> 11, s = row & 2047;
                    float v = acc[mf][nf][r] + pos[s * 64 + d];
                    v *= pscale;
                    dst[(((b * NHEADS + h) * S_LEN) + s) * 64 + d] = f2bf(v);
                }
            }
        }
    }
}

// ---------------------------------------------------------------- attention
// grid (32 bh, 16 x): bh in blockIdx.x keeps same-head blocks at id-stride 32
// (one XCD L2). Balance: qt = (x<8) ? 15-x : x-8, so the co-resident pair
// (x, x+8) computes (16-x)+(x+1) = 17 tiles on every CU (bijective over qt).
// 8 waves x 512 thr, QBLK=128, KVBLK=128. l = P x ones on the matrix pipe.
__global__ __launch_bounds__(512, 4) void attn_kernel(
    const unsigned short* __restrict__ qb,
    const unsigned short* __restrict__ kb,
    const unsigned short* __restrict__ vt,
    unsigned short* __restrict__ attnb)
{
    __shared__ unsigned short Klds[2][128 * 64];   // 16KB each
    __shared__ unsigned short Vlds[2][64 * 128];   // 16KB each
    __shared__ unsigned short Plds[8][16 * 64];    // per-wave 2KB; total 80KB

    const int bh = blockIdx.x;
    const int x = blockIdx.y;
    const int qt = (x < 8) ? (15 - x) : (x - 8);  // balanced + XCD-local

    const int lane = threadIdx.x & 63;
    const int w = threadIdx.x >> 6;               // 0..7
    const int lg = lane >> 4, ll = lane & 15;
    const int r8 = lane >> 3, ch = (lane & 7) ^ r8;
    const int r4 = lane >> 4, c16 = lane & 15;    // V-stage decomposition

    const unsigned short* Q = qb + bh * (S_LEN * 64);
    const unsigned short* K = kb + bh * (S_LEN * 64);
    const unsigned short* V = vt + bh * (64 * S_LEN);
    const int q0 = qt * 128 + w * 16;             // wave q-base

    u16x8 qf0 = *(const u16x8*)(Q + (q0 + ll) * 64 + lg * 8);
    u16x8 qf1 = *(const u16x8*)(Q + (q0 + ll) * 64 + 32 + lg * 8);

    // all-ones bf16 fragment for the l-MFMA (1.0bf16 = 0x3F80)
    u16x8 ones;
    #pragma unroll
    for (int i = 0; i < 8; i++) ones[i] = 0x3F80;

    f32x4 o_acc[4] = {};
    f32x4 l_acc = {};

    const int sw0 = ((0 * 4 + lg) ^ (ll & 7)) * 16;
    const int sw1 = ((1 * 4 + lg) ^ (ll & 7)) * 16;
    const char* kb0p0 = (const char*)&Klds[0][0] + ll * 128 + sw0;
    const char* kb0p1 = (const char*)&Klds[0][0] + ll * 128 + sw1;
    const char* kb1p0 = (const char*)&Klds[1][0] + ll * 128 + sw0;
    const char* kb1p1 = (const char*)&Klds[1][0] + ll * 128 + sw1;
    const char* vb0p0 = (const char*)&Vlds[0][0] + ll * 256 + sw0;
    const char* vb0p1 = (const char*)&Vlds[0][0] + ll * 256 + sw1;
    const char* vb1p0 = (const char*)&Vlds[1][0] + ll * 256 + sw0;
    const char* vb1p1 = (const char*)&Vlds[1][0] + ll * 256 + sw1;
    const int E = (ll & 7) << 4;
    char* pwb = (char*)&Plds[w][0] + (((ll * 128) + lg * 8) ^ (E & 16));
    const int pw_o0 = 0 ^ (E & 96), pw_o1 = 32 ^ (E & 96);
    const int pw_o2 = 64 ^ (E & 96), pw_o3 = 96 ^ (E & 96);
    const char* pr0 = (const char*)&Plds[w][0] + ll * 128 + sw0;
    const char* pr1 = (const char*)&Plds[w][0] + ll * 128 + sw1;
    unsigned short* kd0 = &Klds[0][(w * 16) * 64];
    unsigned short* kd1 = &Klds[1][(w * 16) * 64];
    unsigned short* vd0 = &Vlds[0][(w * 8) * 128];
    unsigned short* vd1 = &Vlds[1][(w * 8) * 128];
    const unsigned short* gk  = K + (w * 16 + r8) * 64 + ch * 8;
    const unsigned short* gva = V + (w * 8 + r4) * S_LEN + ((c16 ^ r4) * 8);
    const unsigned short* gvb = V + (w * 8 + 4 + r4) * S_LEN + ((c16 ^ (4 + r4)) * 8);
    const int dthr = w * 16 + ll - lg * 4;

    auto stage2 = [&](unsigned short* kd, unsigned short* vd) {
        gl16(gk, kd);
        gl16(gk + 512, kd + 512);
        gl16(gva, vd);
        gl16(gvb, vd + 512);
        gk += 128 * 64;
        gva += 128;
        gvb += 128;
    };

    auto tile_body = [&](const char* kp0, const char* kp1,
                         const char* vp0, const char* vp1, bool masked, int thr) {
        f32x4 sc[4] = {};
        __builtin_amdgcn_s_setprio(1);
        #pragma unroll
        for (int f = 0; f < 4; f++) {
            const u16x8 kfa = *(const u16x8*)(kp0 + f * 2048);
            sc[f] = mfma16(kfa, qf0, sc[f]);
            const u16x8 kfb = *(const u16x8*)(kp1 + f * 2048);
            sc[f] = mfma16(kfb, qf1, sc[f]);
        }
        __builtin_amdgcn_s_setprio(0);
        if (masked) {
            #pragma unroll
            for (int f = 0; f < 4; f++)
                #pragma unroll
                for (int r = 0; r < 4; r++)
                    if (f * 16 + r > thr) sc[f][r] = -1.0e9f;
        }
        #pragma unroll
        for (int f = 0; f < 4; f++)
            #pragma unroll
            for (int r = 0; r < 4; r++)
                sc[f][r] = __builtin_amdgcn_exp2f(sc[f][r]);
        *(unsigned long long*)(pwb + pw_o0) =
            (unsigned long long)cvtpk(sc[0][0], sc[0][1]) | ((unsigned long long)cvtpk(sc[0][2], sc[0][3]) << 32);
        *(unsigned long long*)(pwb + pw_o1) =
            (unsigned long long)cvtpk(sc[1][0], sc[1][1]) | ((unsigned long long)cvtpk(sc[1][2], sc[1][3]) << 32);
        *(unsigned long long*)(pwb + pw_o2) =
            (unsigned long long)cvtpk(sc[2][0], sc[2][1]) | ((unsigned long long)cvtpk(sc[2][2], sc[2][3]) << 32);
        *(unsigned long long*)(pwb + pw_o3) =
            (unsigned long long)cvtpk(sc[3][0], sc[3][1]) | ((unsigned long long)cvtpk(sc[3][2], sc[3][3]) << 32);
        const u16x8 pf0 = *(const u16x8*)pr0;
        const u16x8 pf1 = *(const u16x8*)pr1;
        __builtin_amdgcn_s_setprio(1);
        #pragma unroll
        for (int f = 0; f < 4; f++) {
            o_acc[f] = mfma16(pf0, *(const u16x8*)(vp0 + f * 4096), o_acc[f]);
            o_acc[f] = mfma16(pf1, *(const u16x8*)(vp1 + f * 4096), o_acc[f]);
        }
        l_acc = mfma16(pf0, ones, l_acc);   // l += P x 1 (matrix pipe)
        l_acc = mfma16(pf1, ones, l_acc);
        __builtin_amdgcn_s_setprio(0);
    };

    auto body128_full = [&](const char* kp0, const char* kp1,
                            const char* vp0, const char* vp1) {
        tile_body(kp0, kp1, vp0, vp1, false, 0);
        tile_body(kp0 + 8192, kp1 + 8192, vp0 + 128, vp1 + 128, false, 0);
    };
    auto body128_diag = [&](const char* kp0, const char* kp1,
                            const char* vp0, const char* vp1) {
        tile_body(kp0, kp1, vp0, vp1, true, dthr);
        if (w >= 4)   // waves 0-3: second half fully masked
            tile_body(kp0 + 8192, kp1 + 8192, vp0 + 128, vp1 + 128, true, dthr - 64);
    };

    stage2(kd0, vd0);                      // tile 0 -> buf0
    __syncthreads();                       // buf0 ready

    int p = 0;
    while (p + 2 <= qt) {                  // two full 128-tiles
        stage2(kd1, vd1);
        body128_full(kb0p0, kb0p1, vb0p0, vb0p1);
        __syncthreads();
        stage2(kd0, vd0);
        body128_full(kb1p0, kb1p1, vb1p0, vb1p1);
        __syncthreads();
        p += 2;
    }
    if (p < qt) {
        stage2(kd1, vd1);
        body128_full(kb0p0, kb0p1, vb0p0, vb0p1);
        __syncthreads();
        body128_diag(kb1p0, kb1p1, vb1p0, vb1p1);
    } else {
        body128_diag(kb0p0, kb0p1, vb0p0, vb0p1);
    }

    const int bb = bh >> 4, h = bh & 15;
    const float lr0 = 1.0f / l_acc[0];
    const float lr1 = 1.0f / l_acc[1];
    const float lr2 = 1.0f / l_acc[2];
    const float lr3 = 1.0f / l_acc[3];
    #pragma unroll
    for (int f = 0; f < 4; f++) {
        const int colbase = h * 64 + f * 16 + ll;
        attnb[(bb * S_LEN + q0 + lg * 4 + 0) * DMODEL + colbase] = f2bf(o_acc[f][0] * lr0);
        attnb[(bb * S_LEN + q0 + lg * 4 + 1) * DMODEL + colbase] = f2bf(o_acc[f][1] * lr1);
        attnb[(bb * S_LEN + q0 + lg * 4 + 2) * DMODEL + colbase] = f2bf(o_acc[f][2] * lr2);
        attnb[(bb * S_LEN + q0 + lg * 4 + 3) * DMODEL + colbase] = f2bf(o_acc[f][3] * lr3);
    }
}

// ---------------------------------------------------------------- out GEMM
// out = attn @ Wo^T + X. 4-phase counted-vmcnt: 128x128 tile, BK=64, 512 thr
// (8 waves 2Mx4N; wave 64x32, acc 4x2), grid (32,8) = 256 blocks = one
// generation. LDS 3 x 32KB. Boundary VMB(4); tail VMB(0).
__global__ __launch_bounds__(512) void gemm_out(
    const unsigned short* __restrict__ Abf,
    const unsigned short* __restrict__ Wbf,
    const float* __restrict__ X,
    float* __restrict__ out)
{
    const unsigned short* __restrict__ W = Wbf + (3u << 20);
    __shared__ unsigned short L[3][16384];   // 32KB each: A @0, B @elem 8192
    const int t = threadIdx.x;               // 0..511
    const int lane = t & 63;
    const int w = t >> 6;
    const int wm = w >> 2, wn = w & 3;
    const int m0 = blockIdx.x * 128;
    const int n0 = blockIdx.y * 128;
    const int ll = lane & 15, lg = lane >> 4;
    const int tr = t >> 3;
    const int ch = (t & 7) ^ (tr & 7);

    f32x4 acc[4][2] = {};

    const unsigned short* gA[2];
    const unsigned short* gB[2];
    #pragma unroll
    for (int i = 0; i < 2; i++) {
        gA[i] = Abf + (m0 + i * 64 + tr) * 1024 + ch * 8;
        gB[i] = W + (n0 + i * 64 + tr) * 1024 + ch * 8;
    }

    const int sw0 = ((0 * 4 + lg) ^ (ll & 7)) * 16;
    const int sw1 = ((1 * 4 + lg) ^ (ll & 7)) * 16;
    const int aBase = (wm * 64 + ll) * 128;             // byte; + mf*2048 + sw
    const int bBase = 16384 + (wn * 32 + ll) * 128;     // byte; + nf*2048 + sw
    const int wdst = w * 8 * 64;                        // elem

    auto stA0 = [&](unsigned short* Ln) { gl16(gA[0], Ln + wdst);        gA[0] += 64; };
    auto stA1 = [&](unsigned short* Ln) { gl16(gA[1], Ln + 4096 + wdst); gA[1] += 64; };
    auto stB0 = [&](unsigned short* Ln) { gl16(gB[0], Ln + 8192 + wdst); gB[0] += 64; };
    auto stB1 = [&](unsigned short* Ln) { gl16(gB[1], Ln + 12288 + wdst); gB[1] += 64; };

    u16x8 bfv[2][2];
    auto loadB = [&](const char* bb) {
        #pragma unroll
        for (int nf = 0; nf < 2; nf++) {
            const char* p = bb + bBase + nf * 2048;
            bfv[nf][0] = *(const u16x8*)(p + sw0);
            bfv[nf][1] = *(const u16x8*)(p + sw1);
        }
    };
    auto quad = [&](int mf, const char* bb) {
        const char* pa = bb + aBase + mf * 2048;
        u16x8 a0 = *(const u16x8*)(pa + sw0);
        u16x8 a1 = *(const u16x8*)(pa + sw1);
        __builtin_amdgcn_s_setprio(1);
        #pragma unroll
        for (int nf = 0; nf < 2; nf++)
            acc[mf][nf] = mfma16(a0, bfv[nf][0], acc[mf][nf]);
        #pragma unroll
        for (int nf = 0; nf < 2; nf++)
            acc[mf][nf] = mfma16(a1, bfv[nf][1], acc[mf][nf]);
        __builtin_amdgcn_s_setprio(0);
    };

    auto ktile = [&](const char* bb, unsigned short* Ln, bool stg) {
        if (stg) stA0(Ln);
        loadB(bb);
        quad(0, bb);
        __builtin_amdgcn_s_barrier();
        if (stg) stA1(Ln);
        quad(1, bb);
        __builtin_amdgcn_s_barrier();
        if (stg) stB0(Ln);
        quad(2, bb);
        __builtin_amdgcn_s_barrier();
        if (stg) stB1(Ln);
        quad(3, bb);
    };

    stA0(L[0]); stA1(L[0]); stB0(L[0]); stB1(L[0]);
    stA0(L[1]); stA1(L[1]); stB0(L[1]); stB1(L[1]);
    VMB(4);                                   // tile 0 published; tile 1 in flight
    #pragma unroll 1
    for (int tt = 0; tt < 4; tt++) {
        ktile((const char*)L[0], L[2], true); VMB(4);
        ktile((const char*)L[1], L[0], true); VMB(4);
        ktile((const char*)L[2], L[1], true); VMB(4);
    }
    ktile((const char*)L[0], L[2], true); VMB(4);
    ktile((const char*)L[1], L[0], true); VMB(4);
    ktile((const char*)L[2], nullptr, false); VMB(0);
    ktile((const char*)L[0], nullptr, false);

    #pragma unroll
    for (int mf = 0; mf < 4; mf++)
        #pragma unroll
        for (int nf = 0; nf < 2; nf++)
            #pragma unroll
            for (int r = 0; r < 4; r++) {
                const int row = m0 + wm * 64 + mf * 16 + lg * 4 + r;
                const int col = n0 + wn * 32 + nf * 16 + ll;
                out[row * 1024 + col] = acc[mf][nf][r] + X[row * 1024 + col];
            }
}

// ---------------------------------------------------------------- launch
extern "C" void kernel_launch(void* const* d_in, const int* in_sizes, int n_in,
                              void* d_out, int out_size, void* d_ws, size_t ws_size,
                              hipStream_t stream) {
    const float* X  = (const float*)d_in[0];
    const float* Wq = (const float*)d_in[1];
    const float* Wk = (const float*)d_in[2];
    const float* Wv = (const float*)d_in[3];
    const float* Wo = (const float*)d_in[4];
    float* out = (float*)d_out;

    char* ws = (char*)d_ws;
    float*          pos  = (float*)(ws);                                   // 512 KB
    unsigned short* Xbf  = (unsigned short*)(ws + (512u << 10));           // 8 MB (reused as attb)
    unsigned short* Wbf  = (unsigned short*)(ws + (512u << 10) + (8u  << 20));  // 8 MB (4 stacked)
    unsigned short* qb   = (unsigned short*)(ws + (512u << 10) + (16u << 20));
    unsigned short* kb   = (unsigned short*)(ws + (512u << 10) + (24u << 20));
    unsigned short* vt   = (unsigned short*)(ws + (512u << 10) + (32u << 20));
    unsigned short* attb = Xbf;   // Xbf dead after gemm_qkv; reuse for attn output

    cvt5<<<dim3(4608), dim3(256), 0, stream>>>(X, Wq, Wk, Wv, Wo, Xbf, Wbf, pos);
    gemm_qkv<<<dim3(16, 16), dim3(512), 0, stream>>>(Xbf, Wbf, pos, qb, kb, vt);
    attn_kernel<<<dim3(32, 16), dim3(512), 0, stream>>>(qb, kb, vt, attb);
    gemm_out<<<dim3(32, 8), dim3(512), 0, stream>>>(attb, Wbf, X, out);
}